// Round 15
// baseline (414.082 us; speedup 1.0000x reference)
//
#include <hip/hip_runtime.h>
#include <hip/hip_bf16.h>
#include <stdint.h>

#define B_   4
#define L_   2048
#define D_   1024
#define H_   16
#define DH_  64
#define DFF_ 4096
#define EPS_ 1e-5f

typedef short s16x8 __attribute__((ext_vector_type(8)));
typedef short s16x4 __attribute__((ext_vector_type(4)));
typedef float f32x4 __attribute__((ext_vector_type(4)));

static __device__ __forceinline__ short f2bf(float f) {
    return __builtin_bit_cast(short, __float2bfloat16(f));
}

static __device__ __forceinline__ void gload_lds16(const void* g, void* l) {
    __builtin_amdgcn_global_load_lds(
        (const __attribute__((address_space(1))) uint32_t*)g,
        (__attribute__((address_space(3))) uint32_t*)l, 16, 0, 0);
}

// ---------------- transpose + f32 -> bf16 convert (weights, once) -------------
__global__ __launch_bounds__(256) void transpose_kernel(
    const float* __restrict__ in, short* __restrict__ out, int R, int C)
{
    __shared__ float tile[32][33];
    const int bx = blockIdx.x * 32, by = blockIdx.y * 32;
    const int tx = threadIdx.x & 31, ty = threadIdx.x >> 5;  // 32 x 8
#pragma unroll
    for (int i = 0; i < 32; i += 8)
        tile[ty + i][tx] = in[(size_t)(by + ty + i) * C + bx + tx];
    __syncthreads();
#pragma unroll
    for (int i = 0; i < 32; i += 8)
        out[(size_t)(bx + ty + i) * R + by + tx] = f2bf(tile[tx][ty + i]);
}

// ---------------- concat 3 bias vectors (1024 each) -----------------------------
__global__ __launch_bounds__(256) void concat3_kernel(
    const float* __restrict__ a, const float* __restrict__ b,
    const float* __restrict__ c, float* __restrict__ o)
{
    const int i = blockIdx.x * 256 + threadIdx.x;   // 0..3071
    o[i] = (i < 1024) ? a[i] : (i < 2048 ? b[i - 1024] : c[i - 2048]);
}

// ---------------- V transpose: [B*L][D] bf16 -> [(b*H+h)*DH+d][L] bf16 ---------
__global__ __launch_bounds__(256) void vtrans_kernel(
    const short* __restrict__ V, short* __restrict__ Vt)
{
    __shared__ short t[64][72];
    const int l0 = blockIdx.x * 64;
    const int bh = blockIdx.y;          // b*H + h
    const int b = bh >> 4, h = bh & 15;
    const int tid = threadIdx.x;
    const int rr = tid >> 3, cc = tid & 7;
#pragma unroll
    for (int i = 0; i < 2; ++i) {
        const int row = i * 32 + rr;
        *(s16x8*)&t[row][cc * 8] =
            *(const s16x8*)(V + (size_t)(b * L_ + l0 + row) * D_ + h * DH_ + cc * 8);
    }
    __syncthreads();
#pragma unroll
    for (int i = 0; i < 2; ++i) {
        const int d = i * 32 + rr;
        const int lp0 = cc * 8;
        s16x8 o;
#pragma unroll
        for (int j = 0; j < 8; ++j) o[j] = t[lp0 + j][d];
        *(s16x8*)(Vt + ((size_t)bh * DH_ + d) * L_ + l0 + lp0) = o;
    }
}

// ---------------- layernorm: f32 in -> bf16 out --------------------------------
__global__ __launch_bounds__(256) void ln_kernel(
    const float* __restrict__ x, const float* __restrict__ g,
    const float* __restrict__ bta, short* __restrict__ out)
{
    __shared__ float sm[8];
    const int row = blockIdx.x;
    const int t = threadIdx.x;
    const float4 v = ((const float4*)(x + (size_t)row * D_))[t];
    float s1 = v.x + v.y + v.z + v.w;
    float s2 = v.x * v.x + v.y * v.y + v.z * v.z + v.w * v.w;
#pragma unroll
    for (int off = 1; off < 64; off <<= 1) {
        s1 += __shfl_xor(s1, off);
        s2 += __shfl_xor(s2, off);
    }
    if ((t & 63) == 0) { sm[t >> 6] = s1; sm[4 + (t >> 6)] = s2; }
    __syncthreads();
    s1 = sm[0] + sm[1] + sm[2] + sm[3];
    s2 = sm[4] + sm[5] + sm[6] + sm[7];
    const float mu  = s1 * (1.f / D_);
    const float var = s2 * (1.f / D_) - mu * mu;
    const float rs  = rsqrtf(var + EPS_);
    const float4 gv = ((const float4*)g)[t];
    const float4 bv = ((const float4*)bta)[t];
    s16x4 o;
    o[0] = f2bf((v.x - mu) * rs * gv.x + bv.x);
    o[1] = f2bf((v.y - mu) * rs * gv.y + bv.y);
    o[2] = f2bf((v.z - mu) * rs * gv.z + bv.z);
    o[3] = f2bf((v.w - mu) * rs * gv.w + bv.w);
    *(s16x4*)(out + (size_t)row * D_ + t * 4) = o;
}

// ---------------- GEMM: C[M,N] = A[M,K](bf16) @ Bt[N,K]^T (bf16) + epilogue ----
// R10 structure: 128M x 256N tile, 512 threads (8 waves 2x4), ring LDS,
// one barrier per K-step(32), counted vmcnt, T1 chunked XCD swizzle.
// DEPTH=3: 3-ring (72 KB, 2 blk/CU), prefetch t+1, vmcnt(3)
// DEPTH=4: 4-ring (96 KB, 1 blk/CU), prefetch t+2, vmcnt(6)
// MODE 1: bf16=relu(acc+bias); 2: f32=acc+bias+res; 3: bf16 QKV-split.
template <int MODE, int DEPTH>
__global__ __launch_bounds__(512) void gemm_kernel(
    const short* __restrict__ A, const short* __restrict__ Bt,
    const float* __restrict__ bias, const float* __restrict__ res,
    void* __restrict__ out, int M, int N, int K)
{
    __shared__ short As[DEPTH][128 * 32];
    __shared__ short Bs[DEPTH][256 * 32];

    // ---- T1 chunked XCD swizzle (bijective; nwg % 8 == 0) ----
    const int nx = gridDim.x;
    const int flat = blockIdx.y * nx + blockIdx.x;
    const int nper = (nx * gridDim.y) >> 3;
    const int nid = (flat & 7) * nper + (flat >> 3);
    const int m0 = (nid / nx) * 128;
    const int n0 = (nid % nx) * 256;

    const int tid = threadIdx.x;
    const int w = tid >> 6, l = tid & 63;
    const int wm = w >> 2, wn = w & 3;
    const int lg = l >> 4, li = l & 15;

    // A staging: 1 issue/thread; B staging: 2 issues/thread (chunk pre-swizzled)
    const int arow = tid >> 2;
    const int ach = (tid & 3) ^ ((arow >> 1) & 3);
    const short* aSrc = A + (size_t)(m0 + arow) * K + ach * 8;
    const int adst = tid * 8;
    const short* bSrc[2];
    int bdst[2];
#pragma unroll
    for (int i = 0; i < 2; ++i) {
        const int cid = i * 512 + tid;
        const int row = cid >> 2;
        const int ch = (cid & 3) ^ ((row >> 1) & 3);
        bSrc[i] = Bt + (size_t)(n0 + row) * K + ch * 8;
        bdst[i] = cid * 8;
    }

    // fragment read offsets (swizzled)
    int aoff[4], boff[4];
#pragma unroll
    for (int m = 0; m < 4; ++m) {
        const int rowA = wm * 64 + m * 16 + li;
        aoff[m] = rowA * 32 + ((lg ^ ((rowA >> 1) & 3)) * 8);
    }
#pragma unroll
    for (int n = 0; n < 4; ++n) {
        const int rowB = wn * 64 + n * 16 + li;
        boff[n] = rowB * 32 + ((lg ^ ((rowB >> 1) & 3)) * 8);
    }

    f32x4 acc[4][4] = {};
    const int nT = K >> 5;

    // prologue: stage tile 0 into ring slot 0 (+ tile 1 into slot 1 for DEPTH=4)
    gload_lds16(aSrc, &As[0][adst]);
#pragma unroll
    for (int i = 0; i < 2; ++i) gload_lds16(bSrc[i], &Bs[0][bdst[i]]);
    if constexpr (DEPTH == 4) {
        gload_lds16(aSrc + 32, &As[1][adst]);
#pragma unroll
        for (int i = 0; i < 2; ++i) gload_lds16(bSrc[i] + 32, &Bs[1][bdst[i]]);
    }

    int cur = 0;
    int wslot = (DEPTH == 4) ? 2 : 1;
    for (int t = 0; t < nT; ++t) {
        const int pf = t + ((DEPTH == 4) ? 2 : 1);
        if (pf < nT) {
            const int k1 = pf << 5;
            gload_lds16(aSrc + k1, &As[wslot][adst]);
#pragma unroll
            for (int i = 0; i < 2; ++i) gload_lds16(bSrc[i] + k1, &Bs[wslot][bdst[i]]);
            if constexpr (DEPTH == 4)
                asm volatile("s_waitcnt vmcnt(6)" ::: "memory");
            else
                asm volatile("s_waitcnt vmcnt(3)" ::: "memory");
        } else if (DEPTH == 4 && t + 1 < nT) {
            asm volatile("s_waitcnt vmcnt(3)" ::: "memory");
        } else {
            asm volatile("s_waitcnt vmcnt(0)" ::: "memory");
        }
        __builtin_amdgcn_s_barrier();
        __builtin_amdgcn_sched_barrier(0);

        const short* as = &As[cur][0];
        const short* bs = &Bs[cur][0];
        s16x8 af[4], bf[4];
#pragma unroll
        for (int m = 0; m < 4; ++m) af[m] = *(const s16x8*)&as[aoff[m]];
#pragma unroll
        for (int n = 0; n < 4; ++n) bf[n] = *(const s16x8*)&bs[boff[n]];
#pragma unroll
        for (int m = 0; m < 4; ++m)
#pragma unroll
            for (int n = 0; n < 4; ++n)
                acc[m][n] = __builtin_amdgcn_mfma_f32_16x16x32_bf16(
                    af[m], bf[n], acc[m][n], 0, 0, 0);

        cur = (cur + 1 == DEPTH) ? 0 : cur + 1;
        wslot = (wslot + 1 == DEPTH) ? 0 : wslot + 1;
    }

#pragma unroll
    for (int m = 0; m < 4; ++m) {
#pragma unroll
        for (int n = 0; n < 4; ++n) {
            const int col = n0 + wn * 64 + n * 16 + li;
            const float bv = bias[col];
#pragma unroll
            for (int r = 0; r < 4; ++r) {
                const int row = m0 + wm * 64 + m * 16 + lg * 4 + r;
                float v = acc[m][n][r] + bv;
                if (MODE == 1) v = v > 0.f ? v : 0.f;
                if (MODE == 2) {
                    float* o = (float*)out;
                    o[(size_t)row * N + col] = v + res[(size_t)row * N + col];
                } else if (MODE == 3) {
                    short* o = (short*)out;
                    o[(size_t)(col >> 10) * (8192ull * 1024) +
                      (size_t)row * 1024 + (col & 1023)] = f2bf(v);
                } else {
                    short* o = (short*)out;
                    o[(size_t)row * N + col] = f2bf(v);
                }
            }
        }
    }
}

// ---------------- flash attention (causal): 256-row q blocks, 2 q-tiles/wave ----
// grid (8, H, B); 512 threads; wave w owns 32 q-rows (A: qwA..+15, B: +16..+31).
// KV tiles of 64, 2-ring LDS + tail barrier, counted vmcnt(2).
// Swapped QK^T (K/V fragments shared by both q-tiles -> LDS reads and staging
// bytes per MFMA halve). exp2 softmax, defer-max 11.5. Wave-uniform tile skip.
// Balance: qblk = ((xx+b)&1) ? 7-u : u with u=(pr+b)&3 — bijective per (h,b),
// consecutive block-pair total constant, b-mixing decorrelates co-residents.
__global__ __launch_bounds__(512) void attn_kernel(
    const short* __restrict__ Q, const short* __restrict__ K,
    const short* __restrict__ Vt, short* __restrict__ O)
{
    __shared__ short Kbuf[2][64 * 64];
    __shared__ short Vbuf[2][64 * 64];
    __shared__ short Ps[8][2][16 * 72];   // per-wave, per-q-tile P [16 q][64 kv + pad]

    const int xx = blockIdx.x;          // 0..7
    const int h = blockIdx.y, b = blockIdx.z;
    const int pr = xx >> 1;
    const int u = (pr + b) & 3;
    const int qblk = ((xx + b) & 1) ? (7 - u) : u;   // balanced causal work
    const int tid = threadIdx.x;
    const int w = tid >> 6, l = tid & 63;
    const int lg = l >> 4, li = l & 15;
    const size_t headQ = ((size_t)b * L_) * D_ + (size_t)h * DH_;
    const size_t headV = ((size_t)(b * H_ + h) * DH_) * L_;
    const int q0 = qblk * 256;
    const int qwA = q0 + w * 32;
    const int qwB = qwA + 16;
    const float sc2 = 0.125f * 1.44269504f;   // scale * log2(e)

    s16x8 qfA[2], qfB[2];
    {
        const short* qa = Q + headQ + (size_t)(qwA + li) * D_;
        qfA[0] = *(const s16x8*)(qa + lg * 8);
        qfA[1] = *(const s16x8*)(qa + 32 + lg * 8);
        const short* qb = Q + headQ + (size_t)(qwB + li) * D_;
        qfB[0] = *(const s16x8*)(qb + lg * 8);
        qfB[1] = *(const s16x8*)(qb + 32 + lg * 8);
    }

    const int srow = tid >> 3;
    const int schk = (tid & 7) ^ (srow & 7);
    const short* kSrc = K + headQ + (size_t)srow * D_ + schk * 8;
    const short* vSrc = Vt + headV + (size_t)srow * L_ + schk * 8;

    int koff0[4], koff1[4];
#pragma unroll
    for (int blk = 0; blk < 4; ++blk) {
        const int row = blk * 16 + li;
        const int hh = row & 7;
        koff0[blk] = row * 64 + ((lg ^ hh) * 8);
        koff1[blk] = row * 64 + (((lg + 4) ^ hh) * 8);
    }

    float mA = -1e30f, lA = 0.f, mB = -1e30f, lB = 0.f;
    f32x4 oaccA[4] = {}, oaccB[4] = {};
    short* pwA = &Ps[w][0][0];
    short* pwB = &Ps[w][1][0];

    const int nt = (qblk + 1) * 4;

    gload_lds16(kSrc, &Kbuf[0][tid * 8]);
    gload_lds16(vSrc, &Vbuf[0][tid * 8]);

    for (int t = 0; t < nt; ++t) {
        const int kv0 = t * 64;
        if (t + 1 < nt) {
            const int nkv = kv0 + 64;
            const int nb = (t + 1) & 1;
            gload_lds16(kSrc + (size_t)nkv * D_, &Kbuf[nb][tid * 8]);
            gload_lds16(vSrc + nkv, &Vbuf[nb][tid * 8]);
            asm volatile("s_waitcnt vmcnt(2)" ::: "memory");
        } else {
            asm volatile("s_waitcnt vmcnt(0)" ::: "memory");
        }
        __builtin_amdgcn_s_barrier();
        __builtin_amdgcn_sched_barrier(0);

        if (kv0 <= qwB + 15) {   // wave-uniform: tile has unmasked work
            const short* kb = &Kbuf[t & 1][0];
            const short* vb = &Vbuf[t & 1][0];

            // ---- QK^T swapped for both q-tiles (kf shared) ----
            f32x4 sA[4], sB[4];
            __builtin_amdgcn_s_setprio(1);
#pragma unroll
            for (int blk = 0; blk < 4; ++blk) {
                const s16x8 kf0 = *(const s16x8*)&kb[koff0[blk]];
                const s16x8 kf1 = *(const s16x8*)&kb[koff1[blk]];
                f32x4 cA = {0.f, 0.f, 0.f, 0.f};
                cA = __builtin_amdgcn_mfma_f32_16x16x32_bf16(kf0, qfA[0], cA, 0, 0, 0);
                cA = __builtin_amdgcn_mfma_f32_16x16x32_bf16(kf1, qfA[1], cA, 0, 0, 0);
                sA[blk] = cA;
                f32x4 cB = {0.f, 0.f, 0.f, 0.f};
                cB = __builtin_amdgcn_mfma_f32_16x16x32_bf16(kf0, qfB[0], cB, 0, 0, 0);
                cB = __builtin_amdgcn_mfma_f32_16x16x32_bf16(kf1, qfB[1], cB, 0, 0, 0);
                sB[blk] = cB;
            }
            __builtin_amdgcn_s_setprio(0);

            // ---- causal masks (only diagonal-crossing tiles) ----
            if (kv0 + 63 > qwA) {
                const int qA = qwA + li;
#pragma unroll
                for (int blk = 0; blk < 4; ++blk) {
                    const int kvb = kv0 + blk * 16 + lg * 4;
#pragma unroll
                    for (int r = 0; r < 4; ++r)
                        if (kvb + r > qA) sA[blk][r] = -1e30f;
                }
            }
            if (kv0 + 63 > qwB) {
                const int qB = qwB + li;
#pragma unroll
                for (int blk = 0; blk < 4; ++blk) {
                    const int kvb = kv0 + blk * 16 + lg * 4;
#pragma unroll
                    for (int r = 0; r < 4; ++r)
                        if (kvb + r > qB) sB[blk][r] = -1e30f;
                }
            }

            // ---- online softmax (log2 domain), defer-max ----
            float mmA = fmaxf(fmaxf(sA[0][0], sA[0][1]), fmaxf(sA[0][2], sA[0][3]));
            float mmB = fmaxf(fmaxf(sB[0][0], sB[0][1]), fmaxf(sB[0][2], sB[0][3]));
#pragma unroll
            for (int blk = 1; blk < 4; ++blk) {
                mmA = fmaxf(mmA, fmaxf(fmaxf(sA[blk][0], sA[blk][1]),
                                       fmaxf(sA[blk][2], sA[blk][3])));
                mmB = fmaxf(mmB, fmaxf(fmaxf(sB[blk][0], sB[blk][1]),
                                       fmaxf(sB[blk][2], sB[blk][3])));
            }
            mmA = fmaxf(mmA, __shfl_xor(mmA, 16));
            mmA = fmaxf(mmA, __shfl_xor(mmA, 32));
            mmB = fmaxf(mmB, __shfl_xor(mmB, 16));
            mmB = fmaxf(mmB, __shfl_xor(mmB, 32));
            const float mxA = mmA * sc2;
            const float mxB = mmB * sc2;

            const bool ok = (mxA <= mA + 11.5f) && (mxB <= mB + 11.5f);
            if (__all(ok)) {
                float sumA = 0.f;
#pragma unroll
                for (int blk = 0; blk < 4; ++blk) {
                    s16x4 pk;
#pragma unroll
                    for (int r = 0; r < 4; ++r) {
                        const float p = __builtin_amdgcn_exp2f(
                            fmaf(sA[blk][r], sc2, -mA));
                        sumA += p;
                        pk[r] = f2bf(p);
                    }
                    *(s16x4*)&pwA[li * 72 + blk * 16 + lg * 4] = pk;
                }
                sumA += __shfl_xor(sumA, 16);
                sumA += __shfl_xor(sumA, 32);
                lA += sumA;
                float sumB = 0.f;
#pragma unroll
                for (int blk = 0; blk < 4; ++blk) {
                    s16x4 pk;
#pragma unroll
                    for (int r = 0; r < 4; ++r) {
                        const float p = __builtin_amdgcn_exp2f(
                            fmaf(sB[blk][r], sc2, -mB));
                        sumB += p;
                        pk[r] = f2bf(p);
                    }
                    *(s16x4*)&pwB[li * 72 + blk * 16 + lg * 4] = pk;
                }
                sumB += __shfl_xor(sumB, 16);
                sumB += __shfl_xor(sumB, 32);
                lB += sumB;
            } else {
                const float mnA = fmaxf(mA, mxA);
                const float facA = __builtin_amdgcn_exp2f(mA - mnA);
                mA = mnA;
                float sumA = 0.f;
#pragma unroll
                for (int blk = 0; blk < 4; ++blk) {
                    s16x4 pk;
#pragma unroll
                    for (int r = 0; r < 4; ++r) {
                        const float p = __builtin_amdgcn_exp2f(
                            fmaf(sA[blk][r], sc2, -mnA));
                        sumA += p;
                        pk[r] = f2bf(p);
                    }
                    *(s16x4*)&pwA[li * 72 + blk * 16 + lg * 4] = pk;
                }
                sumA += __shfl_xor(sumA, 16);
                sumA += __shfl_xor(sumA, 32);
                lA = lA * facA + sumA;
#pragma unroll
                for (int d = 0; d < 4; ++d)
#pragma unroll
                    for (int r = 0; r < 4; ++r)
                        oaccA[d][r] *= facA;
                const float mnB = fmaxf(mB, mxB);
                const float facB = __builtin_amdgcn_exp2f(mB - mnB);
                mB = mnB;
                float sumB = 0.f;
#pragma unroll
                for (int blk = 0; blk < 4; ++blk) {
                    s16x4 pk;
#pragma unroll
                    for (int r = 0; r < 4; ++r) {
                        const float p = __builtin_amdgcn_exp2f(
                            fmaf(sB[blk][r], sc2, -mnB));
                        sumB += p;
                        pk[r] = f2bf(p);
                    }
                    *(s16x4*)&pwB[li * 72 + blk * 16 + lg * 4] = pk;
                }
                sumB += __shfl_xor(sumB, 16);
                sumB += __shfl_xor(sumB, 32);
                lB = lB * facB + sumB;
#pragma unroll
                for (int d = 0; d < 4; ++d)
#pragma unroll
                    for (int r = 0; r < 4; ++r)
                        oaccB[d][r] *= facB;
            }

            asm volatile("s_waitcnt lgkmcnt(0)" ::: "memory");
            __builtin_amdgcn_sched_barrier(0);
            const s16x8 paA0 = *(const s16x8*)&pwA[li * 72 + lg * 8];
            const s16x8 paA1 = *(const s16x8*)&pwA[li * 72 + 32 + lg * 8];
            const s16x8 paB0 = *(const s16x8*)&pwB[li * 72 + lg * 8];
            const s16x8 paB1 = *(const s16x8*)&pwB[li * 72 + 32 + lg * 8];

            // ---- PV for both q-tiles (vf shared) ----
            __builtin_amdgcn_s_setprio(1);
#pragma unroll
            for (int dblk = 0; dblk < 4; ++dblk) {
                const s16x8 vf0 = *(const s16x8*)&vb[koff0[dblk]];
                const s16x8 vf1 = *(const s16x8*)&vb[koff1[dblk]];
                oaccA[dblk] = __builtin_amdgcn_mfma_f32_16x16x32_bf16(vf0, paA0, oaccA[dblk], 0, 0, 0);
                oaccA[dblk] = __builtin_amdgcn_mfma_f32_16x16x32_bf16(vf1, paA1, oaccA[dblk], 0, 0, 0);
                oaccB[dblk] = __builtin_amdgcn_mfma_f32_16x16x32_bf16(vf0, paB0, oaccB[dblk], 0, 0, 0);
                oaccB[dblk] = __builtin_amdgcn_mfma_f32_16x16x32_bf16(vf1, paB1, oaccB[dblk], 0, 0, 0);
            }
            __builtin_amdgcn_s_setprio(0);
        }

        __builtin_amdgcn_s_barrier();   // all waves done reading buf[t&1]
    }

    const float invA = 1.f / lA;
    const float invB = 1.f / lB;
#pragma unroll
    for (int dblk = 0; dblk < 4; ++dblk) {
        s16x4 oa, ob;
#pragma unroll
        for (int r = 0; r < 4; ++r) {
            oa[r] = f2bf(oaccA[dblk][r] * invA);
            ob[r] = f2bf(oaccB[dblk][r] * invB);
        }
        *(s16x4*)(O + headQ + (size_t)(qwA + li) * D_ + dblk * 16 + lg * 4) = oa;
        *(s16x4*)(O + headQ + (size_t)(qwB + li) * D_ + dblk * 16 + lg * 4) = ob;
    }
}

// ---------------- launch --------------------------------------------------------
extern "C" void kernel_launch(void* const* d_in, const int* in_sizes, int n_in,
                              void* d_out, int out_size, void* d_ws, size_t ws_size,
                              hipStream_t stream)
{
    const float* X   = (const float*)d_in[0];
    const float* WQ  = (const float*)d_in[1];
    const float* bQ  = (const float*)d_in[2];
    const float* WK  = (const float*)d_in[3];
    const float* bK  = (const float*)d_in[4];
    const float* WV  = (const float*)d_in[5];
    const float* bV  = (const float*)d_in[6];
    const float* WO  = (const float*)d_in[7];
    const float* bO  = (const float*)d_in[8];
    const float* W1  = (const float*)d_in[9];
    const float* b1  = (const float*)d_in[10];
    const float* W2  = (const float*)d_in[11];
    const float* b2  = (const float*)d_in[12];
    const float* g1  = (const float*)d_in[13];
    const float* be1 = (const float*)d_in[14];
    const float* g2  = (const float*)d_in[15];
    const float* be2 = (const float*)d_in[16];
    float* out = (float*)d_out;

    char* ws = (char*)d_ws;
    const size_t MB = 1u << 20;
    short* WQKVt = (short*)(ws + 0 * MB);  // [3072][1024] (WQt|WKt|WVt contiguous)
    short* WOt = (short*)(ws + 6 * MB);
    short* W1t = (short*)(ws + 8 * MB);    // [4096][1024]
    short* W2t = (short*)(ws + 16 * MB);   // [1024][4096]
    short* Xn  = (short*)(ws + 24 * MB);   // [8192][1024] (LN1, reused for LN2)
    short* Qb  = (short*)(ws + 40 * MB);   // [8192][1024]; Kb=+16MB, Vb=+32MB
    short* Vb  = (short*)(ws + 72 * MB);
    short* Vtb = (short*)(ws + 88 * MB);   // [64*64][2048] V^T
    float* bQKV = (float*)(ws + 88 * MB);  // 3072 f32, dead before vtrans writes Vtb
    short* AV  = (short*)(ws + 72 * MB);   // reuses Vb after vtrans
    short* H1  = (short*)(ws + 40 * MB);   // [8192][4096], reuses Q/K/V (dead)

    const dim3 tb(256);

    transpose_kernel<<<dim3(32, 32), tb, 0, stream>>>(WQ, WQKVt, 1024, 1024);
    transpose_kernel<<<dim3(32, 32), tb, 0, stream>>>(WK, WQKVt + 1024 * 1024, 1024, 1024);
    transpose_kernel<<<dim3(32, 32), tb, 0, stream>>>(WV, WQKVt + 2 * 1024 * 1024, 1024, 1024);
    transpose_kernel<<<dim3(32, 32), tb, 0, stream>>>(WO, WOt, 1024, 1024);
    transpose_kernel<<<dim3(128, 32), tb, 0, stream>>>(W1, W1t, 1024, 4096);
    transpose_kernel<<<dim3(32, 128), tb, 0, stream>>>(W2, W2t, 4096, 1024);
    concat3_kernel<<<dim3(12), tb, 0, stream>>>(bQ, bK, bV, bQKV);

    ln_kernel<<<8192, tb, 0, stream>>>(X, g1, be1, Xn);

    // fused QKV GEMM: N=3072, split outputs to Qb/Kb/Vb
    gemm_kernel<3, 3><<<dim3(12, 64), dim3(512), 0, stream>>>(
        Xn, WQKVt, bQKV, nullptr, Qb, 8192, 3072, 1024);

    vtrans_kernel<<<dim3(L_ / 64, B_ * H_), tb, 0, stream>>>(Vb, Vtb);

    attn_kernel<<<dim3(L_ / 256, H_, B_), dim3(512), 0, stream>>>(
        Qb, Qb + 8192ull * 1024, Vtb, AV);

    gemm_kernel<2, 3><<<dim3(4, 64), dim3(512), 0, stream>>>(
        AV, WOt, bO, X, out, 8192, 1024, 1024);

    ln_kernel<<<8192, tb, 0, stream>>>(out, g2, be2, Xn);

    gemm_kernel<1, 3><<<dim3(16, 64), dim3(512), 0, stream>>>(
        Xn, W1t, b1, nullptr, H1, 8192, 4096, 1024);
    gemm_kernel<2, 4><<<dim3(4, 64), dim3(512), 0, stream>>>(
        H1, W2t, b2, out, out, 8192, 1024, 4096);
}

// Round 16
// 366.692 us; speedup vs baseline: 1.1292x; 1.1292x over previous
//
#include <hip/hip_runtime.h>
#include <hip/hip_bf16.h>
#include <stdint.h>

#define B_   4
#define L_   2048
#define D_   1024
#define H_   16
#define DH_  64
#define DFF_ 4096
#define EPS_ 1e-5f

typedef short s16x8 __attribute__((ext_vector_type(8)));
typedef short s16x4 __attribute__((ext_vector_type(4)));
typedef float f32x4 __attribute__((ext_vector_type(4)));

static __device__ __forceinline__ short f2bf(float f) {
    return __builtin_bit_cast(short, __float2bfloat16(f));
}

static __device__ __forceinline__ void gload_lds16(const void* g, void* l) {
    __builtin_amdgcn_global_load_lds(
        (const __attribute__((address_space(1))) uint32_t*)g,
        (__attribute__((address_space(3))) uint32_t*)l, 16, 0, 0);
}

// ---------------- transpose + f32 -> bf16 convert (weights, once) -------------
__global__ __launch_bounds__(256) void transpose_kernel(
    const float* __restrict__ in, short* __restrict__ out, int R, int C)
{
    __shared__ float tile[32][33];
    const int bx = blockIdx.x * 32, by = blockIdx.y * 32;
    const int tx = threadIdx.x & 31, ty = threadIdx.x >> 5;  // 32 x 8
#pragma unroll
    for (int i = 0; i < 32; i += 8)
        tile[ty + i][tx] = in[(size_t)(by + ty + i) * C + bx + tx];
    __syncthreads();
#pragma unroll
    for (int i = 0; i < 32; i += 8)
        out[(size_t)(bx + ty + i) * R + by + tx] = f2bf(tile[tx][ty + i]);
}

// ---------------- concat 3 bias vectors (1024 each) -----------------------------
__global__ __launch_bounds__(256) void concat3_kernel(
    const float* __restrict__ a, const float* __restrict__ b,
    const float* __restrict__ c, float* __restrict__ o)
{
    const int i = blockIdx.x * 256 + threadIdx.x;   // 0..3071
    o[i] = (i < 1024) ? a[i] : (i < 2048 ? b[i - 1024] : c[i - 2048]);
}

// ---------------- V transpose: [B*L][D] bf16 -> [(b*H+h)*DH+d][L] bf16 ---------
__global__ __launch_bounds__(256) void vtrans_kernel(
    const short* __restrict__ V, short* __restrict__ Vt)
{
    __shared__ short t[64][72];
    const int l0 = blockIdx.x * 64;
    const int bh = blockIdx.y;          // b*H + h
    const int b = bh >> 4, h = bh & 15;
    const int tid = threadIdx.x;
    const int rr = tid >> 3, cc = tid & 7;
#pragma unroll
    for (int i = 0; i < 2; ++i) {
        const int row = i * 32 + rr;
        *(s16x8*)&t[row][cc * 8] =
            *(const s16x8*)(V + (size_t)(b * L_ + l0 + row) * D_ + h * DH_ + cc * 8);
    }
    __syncthreads();
#pragma unroll
    for (int i = 0; i < 2; ++i) {
        const int d = i * 32 + rr;
        const int lp0 = cc * 8;
        s16x8 o;
#pragma unroll
        for (int j = 0; j < 8; ++j) o[j] = t[lp0 + j][d];
        *(s16x8*)(Vt + ((size_t)bh * DH_ + d) * L_ + l0 + lp0) = o;
    }
}

// ---------------- layernorm: f32 in -> bf16 out --------------------------------
__global__ __launch_bounds__(256) void ln_kernel(
    const float* __restrict__ x, const float* __restrict__ g,
    const float* __restrict__ bta, short* __restrict__ out)
{
    __shared__ float sm[8];
    const int row = blockIdx.x;
    const int t = threadIdx.x;
    const float4 v = ((const float4*)(x + (size_t)row * D_))[t];
    float s1 = v.x + v.y + v.z + v.w;
    float s2 = v.x * v.x + v.y * v.y + v.z * v.z + v.w * v.w;
#pragma unroll
    for (int off = 1; off < 64; off <<= 1) {
        s1 += __shfl_xor(s1, off);
        s2 += __shfl_xor(s2, off);
    }
    if ((t & 63) == 0) { sm[t >> 6] = s1; sm[4 + (t >> 6)] = s2; }
    __syncthreads();
    s1 = sm[0] + sm[1] + sm[2] + sm[3];
    s2 = sm[4] + sm[5] + sm[6] + sm[7];
    const float mu  = s1 * (1.f / D_);
    const float var = s2 * (1.f / D_) - mu * mu;
    const float rs  = rsqrtf(var + EPS_);
    const float4 gv = ((const float4*)g)[t];
    const float4 bv = ((const float4*)bta)[t];
    s16x4 o;
    o[0] = f2bf((v.x - mu) * rs * gv.x + bv.x);
    o[1] = f2bf((v.y - mu) * rs * gv.y + bv.y);
    o[2] = f2bf((v.z - mu) * rs * gv.z + bv.z);
    o[3] = f2bf((v.w - mu) * rs * gv.w + bv.w);
    *(s16x4*)(out + (size_t)row * D_ + t * 4) = o;
}

// ---------------- GEMM: C[M,N] = A[M,K](bf16) @ Bt[N,K]^T (bf16) + epilogue ----
// Barrier-amortized variant of R10: 128M x 256N tile, BK=64, 512 threads
// (8 waves 2x4), 3-ring LDS (144 KB, 1 blk/CU), ONE barrier per 32 MFMA
// (vs per 16 at BK=32), counted vmcnt(6), T1 chunked XCD swizzle.
// Swizzle: 64-short rows, chunk' = chunk ^ (row&7), both sides (same geometry
// as attn K-buffer, measured ~2-way conflicts).
// MODE 1: bf16=relu(acc+bias); 2: f32=acc+bias+res; 3: bf16 QKV-split.
template <int MODE>
__global__ __launch_bounds__(512) void gemm_kernel(
    const short* __restrict__ A, const short* __restrict__ Bt,
    const float* __restrict__ bias, const float* __restrict__ res,
    void* __restrict__ out, int M, int N, int K)
{
    __shared__ short As[3][128 * 64];   // 48 KB
    __shared__ short Bs[3][256 * 64];   // 96 KB

    // ---- T1 chunked XCD swizzle (bijective; nwg % 8 == 0) ----
    const int nx = gridDim.x;
    const int flat = blockIdx.y * nx + blockIdx.x;
    const int nper = (nx * gridDim.y) >> 3;
    const int nid = (flat & 7) * nper + (flat >> 3);
    const int m0 = (nid / nx) * 128;
    const int n0 = (nid % nx) * 256;

    const int tid = threadIdx.x;
    const int w = tid >> 6, l = tid & 63;
    const int wm = w >> 2, wn = w & 3;
    const int lg = l >> 4, li = l & 15;

    // A staging: 2 issues/thread; B staging: 4 issues/thread (chunk pre-swizzled)
    const short* aSrc[2];
    int adst[2];
#pragma unroll
    for (int i = 0; i < 2; ++i) {
        const int s = i * 512 + tid;          // 0..1023
        const int row = s >> 3;               // 0..127
        const int ch = (s & 7) ^ (row & 7);
        aSrc[i] = A + (size_t)(m0 + row) * K + ch * 8;
        adst[i] = s * 8;
    }
    const short* bSrc[4];
    int bdst[4];
#pragma unroll
    for (int i = 0; i < 4; ++i) {
        const int s = i * 512 + tid;          // 0..2047
        const int row = s >> 3;               // 0..255
        const int ch = (s & 7) ^ (row & 7);
        bSrc[i] = Bt + (size_t)(n0 + row) * K + ch * 8;
        bdst[i] = s * 8;
    }

    // fragment read offsets (swizzled): desired chunk c = ks*4+lg -> pos c^(row&7)
    int aoff[4][2], boff[4][2];
#pragma unroll
    for (int m = 0; m < 4; ++m)
#pragma unroll
        for (int ks = 0; ks < 2; ++ks) {
            const int rowA = wm * 64 + m * 16 + li;
            aoff[m][ks] = rowA * 64 + (((ks * 4 + lg) ^ (rowA & 7)) * 8);
        }
#pragma unroll
    for (int n = 0; n < 4; ++n)
#pragma unroll
        for (int ks = 0; ks < 2; ++ks) {
            const int rowB = wn * 64 + n * 16 + li;
            boff[n][ks] = rowB * 64 + (((ks * 4 + lg) ^ (rowB & 7)) * 8);
        }

    f32x4 acc[4][4] = {};
    const int nT = K >> 6;

    // prologue: stage tile 0 into ring slot 0 (6 loads/thread)
#pragma unroll
    for (int i = 0; i < 2; ++i) gload_lds16(aSrc[i], &As[0][adst[i]]);
#pragma unroll
    for (int i = 0; i < 4; ++i) gload_lds16(bSrc[i], &Bs[0][bdst[i]]);

    int cur = 0, nxt = 1;
    for (int t = 0; t < nT; ++t) {
        if (t + 1 < nT) {
            const int k1 = (t + 1) << 6;
#pragma unroll
            for (int i = 0; i < 2; ++i) gload_lds16(aSrc[i] + k1, &As[nxt][adst[i]]);
#pragma unroll
            for (int i = 0; i < 4; ++i) gload_lds16(bSrc[i] + k1, &Bs[nxt][bdst[i]]);
            asm volatile("s_waitcnt vmcnt(6)" ::: "memory");
        } else {
            asm volatile("s_waitcnt vmcnt(0)" ::: "memory");
        }
        __builtin_amdgcn_s_barrier();
        __builtin_amdgcn_sched_barrier(0);

        const short* as = &As[cur][0];
        const short* bs = &Bs[cur][0];
        s16x8 af[4][2], bf[4][2];
#pragma unroll
        for (int m = 0; m < 4; ++m)
#pragma unroll
            for (int ks = 0; ks < 2; ++ks)
                af[m][ks] = *(const s16x8*)&as[aoff[m][ks]];
#pragma unroll
        for (int n = 0; n < 4; ++n)
#pragma unroll
            for (int ks = 0; ks < 2; ++ks)
                bf[n][ks] = *(const s16x8*)&bs[boff[n][ks]];
#pragma unroll
        for (int ks = 0; ks < 2; ++ks)
#pragma unroll
            for (int m = 0; m < 4; ++m)
#pragma unroll
                for (int n = 0; n < 4; ++n)
                    acc[m][n] = __builtin_amdgcn_mfma_f32_16x16x32_bf16(
                        af[m][ks], bf[n][ks], acc[m][n], 0, 0, 0);

        cur = nxt;
        nxt = (nxt == 2) ? 0 : nxt + 1;
    }

#pragma unroll
    for (int m = 0; m < 4; ++m) {
#pragma unroll
        for (int n = 0; n < 4; ++n) {
            const int col = n0 + wn * 64 + n * 16 + li;
            const float bv = bias[col];
#pragma unroll
            for (int r = 0; r < 4; ++r) {
                const int row = m0 + wm * 64 + m * 16 + lg * 4 + r;
                float v = acc[m][n][r] + bv;
                if (MODE == 1) v = v > 0.f ? v : 0.f;
                if (MODE == 2) {
                    float* o = (float*)out;
                    o[(size_t)row * N + col] = v + res[(size_t)row * N + col];
                } else if (MODE == 3) {
                    short* o = (short*)out;
                    o[(size_t)(col >> 10) * (8192ull * 1024) +
                      (size_t)row * 1024 + (col & 1023)] = f2bf(v);
                } else {
                    short* o = (short*)out;
                    o[(size_t)row * N + col] = f2bf(v);
                }
            }
        }
    }
}

// ---------------- flash attention (causal): swapped QK^T, 3-ring, vmcnt --------
// R14-proven version. grid (16, H, B); 512 threads; wave w owns 16 q-rows;
// KV tiles of 64. S^T = mfma(K, Q). Causal balance: qblk mixed over (xx, b).
// exp2 softmax, defer-max 11.5. Wave-uniform skip of fully-masked tiles.
__global__ __launch_bounds__(512) void attn_kernel(
    const short* __restrict__ Q, const short* __restrict__ K,
    const short* __restrict__ Vt, short* __restrict__ O)
{
    __shared__ short Kbuf[3][64 * 64];
    __shared__ short Vbuf[3][64 * 64];
    __shared__ short Ps[8][16 * 72];   // per-wave P [16 q][64 kv + pad]

    const int xx = blockIdx.x;          // 0..15
    const int h = blockIdx.y, b = blockIdx.z;
    const int pr = xx >> 1;
    const int u = (pr + b * 2) & 7;
    const int qblk = ((xx + b) & 1) ? (15 - u) : u;   // balanced causal work
    const int tid = threadIdx.x;
    const int w = tid >> 6, l = tid & 63;
    const int lg = l >> 4, li = l & 15;
    const size_t headQ = ((size_t)b * L_) * D_ + (size_t)h * DH_;
    const size_t headV = ((size_t)(b * H_ + h) * DH_) * L_;
    const int q0 = qblk * 128;
    const int qw = q0 + w * 16;
    const float sc2 = 0.125f * 1.44269504f;   // scale * log2(e)

    s16x8 qf[2];
    {
        const short* qr = Q + headQ + (size_t)(qw + li) * D_;
        qf[0] = *(const s16x8*)(qr + lg * 8);
        qf[1] = *(const s16x8*)(qr + 32 + lg * 8);
    }

    const int srow = tid >> 3;
    const int schk = (tid & 7) ^ (srow & 7);
    const short* kSrc = K + headQ + (size_t)srow * D_ + schk * 8;
    const short* vSrc = Vt + headV + (size_t)srow * L_ + schk * 8;

    int koff0[4], koff1[4];
#pragma unroll
    for (int blk = 0; blk < 4; ++blk) {
        const int row = blk * 16 + li;
        const int hh = row & 7;
        koff0[blk] = row * 64 + ((lg ^ hh) * 8);
        koff1[blk] = row * 64 + (((lg + 4) ^ hh) * 8);
    }

    float m_r = -1e30f, l_r = 0.f;
    f32x4 oacc[4] = {};
    short* pw = &Ps[w][0];

    const int nt = 2 * qblk + 2;

    gload_lds16(kSrc, &Kbuf[0][tid * 8]);
    gload_lds16(vSrc, &Vbuf[0][tid * 8]);

    int cur = 0, nxt = 1;
    for (int t = 0; t < nt; ++t) {
        const int kv0 = t * 64;
        if (t + 1 < nt) {
            const int nkv = kv0 + 64;
            gload_lds16(kSrc + (size_t)nkv * D_, &Kbuf[nxt][tid * 8]);
            gload_lds16(vSrc + nkv, &Vbuf[nxt][tid * 8]);
            asm volatile("s_waitcnt vmcnt(2)" ::: "memory");
        } else {
            asm volatile("s_waitcnt vmcnt(0)" ::: "memory");
        }
        __builtin_amdgcn_s_barrier();
        __builtin_amdgcn_sched_barrier(0);

        if (kv0 <= qw + 15) {   // wave-uniform: tile has unmasked work
            const short* kb = &Kbuf[cur][0];
            const short* vb = &Vbuf[cur][0];

            f32x4 s[4];
            __builtin_amdgcn_s_setprio(1);
#pragma unroll
            for (int blk = 0; blk < 4; ++blk) {
                const s16x8 kf0 = *(const s16x8*)&kb[koff0[blk]];
                const s16x8 kf1 = *(const s16x8*)&kb[koff1[blk]];
                f32x4 c = {0.f, 0.f, 0.f, 0.f};
                c = __builtin_amdgcn_mfma_f32_16x16x32_bf16(kf0, qf[0], c, 0, 0, 0);
                c = __builtin_amdgcn_mfma_f32_16x16x32_bf16(kf1, qf[1], c, 0, 0, 0);
                s[blk] = c;
            }
            __builtin_amdgcn_s_setprio(0);

            if (kv0 + 63 > qw) {
                const int q = qw + li;
#pragma unroll
                for (int blk = 0; blk < 4; ++blk) {
                    const int kvb = kv0 + blk * 16 + lg * 4;
#pragma unroll
                    for (int r = 0; r < 4; ++r)
                        if (kvb + r > q) s[blk][r] = -1e30f;
                }
            }

            float mm = fmaxf(fmaxf(s[0][0], s[0][1]), fmaxf(s[0][2], s[0][3]));
#pragma unroll
            for (int blk = 1; blk < 4; ++blk)
                mm = fmaxf(mm, fmaxf(fmaxf(s[blk][0], s[blk][1]),
                                     fmaxf(s[blk][2], s[blk][3])));
            mm = fmaxf(mm, __shfl_xor(mm, 16));
            mm = fmaxf(mm, __shfl_xor(mm, 32));
            const float mxs = mm * sc2;

            float p[4][4];
            if (__all(mxs <= m_r + 11.5f)) {
                float sum = 0.f;
#pragma unroll
                for (int blk = 0; blk < 4; ++blk)
#pragma unroll
                    for (int r = 0; r < 4; ++r) {
                        p[blk][r] = __builtin_amdgcn_exp2f(
                            fmaf(s[blk][r], sc2, -m_r));
                        sum += p[blk][r];
                    }
                sum += __shfl_xor(sum, 16);
                sum += __shfl_xor(sum, 32);
                l_r += sum;
            } else {
                const float mn = fmaxf(m_r, mxs);
                const float fac = __builtin_amdgcn_exp2f(m_r - mn);
                m_r = mn;
                float sum = 0.f;
#pragma unroll
                for (int blk = 0; blk < 4; ++blk)
#pragma unroll
                    for (int r = 0; r < 4; ++r) {
                        p[blk][r] = __builtin_amdgcn_exp2f(
                            fmaf(s[blk][r], sc2, -mn));
                        sum += p[blk][r];
                    }
                sum += __shfl_xor(sum, 16);
                sum += __shfl_xor(sum, 32);
                l_r = l_r * fac + sum;
#pragma unroll
                for (int d = 0; d < 4; ++d)
#pragma unroll
                    for (int r = 0; r < 4; ++r)
                        oacc[d][r] *= fac;
            }

#pragma unroll
            for (int blk = 0; blk < 4; ++blk) {
                s16x4 pk;
#pragma unroll
                for (int r = 0; r < 4; ++r) pk[r] = f2bf(p[blk][r]);
                *(s16x4*)&pw[li * 72 + blk * 16 + lg * 4] = pk;
            }
            asm volatile("s_waitcnt lgkmcnt(0)" ::: "memory");
            __builtin_amdgcn_sched_barrier(0);
            const s16x8 pa0 = *(const s16x8*)&pw[li * 72 + lg * 8];
            const s16x8 pa1 = *(const s16x8*)&pw[li * 72 + 32 + lg * 8];

            __builtin_amdgcn_s_setprio(1);
#pragma unroll
            for (int dblk = 0; dblk < 4; ++dblk) {
                const s16x8 vf0 = *(const s16x8*)&vb[koff0[dblk]];
                const s16x8 vf1 = *(const s16x8*)&vb[koff1[dblk]];
                oacc[dblk] = __builtin_amdgcn_mfma_f32_16x16x32_bf16(vf0, pa0, oacc[dblk], 0, 0, 0);
                oacc[dblk] = __builtin_amdgcn_mfma_f32_16x16x32_bf16(vf1, pa1, oacc[dblk], 0, 0, 0);
            }
            __builtin_amdgcn_s_setprio(0);
        }

        cur = nxt;
        nxt = (nxt == 2) ? 0 : nxt + 1;
    }

    const float inv = 1.f / l_r;
#pragma unroll
    for (int dblk = 0; dblk < 4; ++dblk) {
        s16x4 ov;
#pragma unroll
        for (int r = 0; r < 4; ++r) ov[r] = f2bf(oacc[dblk][r] * inv);
        *(s16x4*)(O + headQ + (size_t)(qw + li) * D_ + dblk * 16 + lg * 4) = ov;
    }
}

// ---------------- launch --------------------------------------------------------
extern "C" void kernel_launch(void* const* d_in, const int* in_sizes, int n_in,
                              void* d_out, int out_size, void* d_ws, size_t ws_size,
                              hipStream_t stream)
{
    const float* X   = (const float*)d_in[0];
    const float* WQ  = (const float*)d_in[1];
    const float* bQ  = (const float*)d_in[2];
    const float* WK  = (const float*)d_in[3];
    const float* bK  = (const float*)d_in[4];
    const float* WV  = (const float*)d_in[5];
    const float* bV  = (const float*)d_in[6];
    const float* WO  = (const float*)d_in[7];
    const float* bO  = (const float*)d_in[8];
    const float* W1  = (const float*)d_in[9];
    const float* b1  = (const float*)d_in[10];
    const float* W2  = (const float*)d_in[11];
    const float* b2  = (const float*)d_in[12];
    const float* g1  = (const float*)d_in[13];
    const float* be1 = (const float*)d_in[14];
    const float* g2  = (const float*)d_in[15];
    const float* be2 = (const float*)d_in[16];
    float* out = (float*)d_out;

    char* ws = (char*)d_ws;
    const size_t MB = 1u << 20;
    short* WQKVt = (short*)(ws + 0 * MB);  // [3072][1024] (WQt|WKt|WVt contiguous)
    short* WOt = (short*)(ws + 6 * MB);
    short* W1t = (short*)(ws + 8 * MB);    // [4096][1024]
    short* W2t = (short*)(ws + 16 * MB);   // [1024][4096]
    short* Xn  = (short*)(ws + 24 * MB);   // [8192][1024] (LN1, reused for LN2)
    short* Qb  = (short*)(ws + 40 * MB);   // [8192][1024]; Kb=+16MB, Vb=+32MB
    short* Vb  = (short*)(ws + 72 * MB);
    short* Vtb = (short*)(ws + 88 * MB);   // [64*64][2048] V^T
    float* bQKV = (float*)(ws + 88 * MB);  // 3072 f32, dead before vtrans writes Vtb
    short* AV  = (short*)(ws + 72 * MB);   // reuses Vb after vtrans
    short* H1  = (short*)(ws + 40 * MB);   // [8192][4096], reuses Q/K/V (dead)

    const dim3 tb(256);

    transpose_kernel<<<dim3(32, 32), tb, 0, stream>>>(WQ, WQKVt, 1024, 1024);
    transpose_kernel<<<dim3(32, 32), tb, 0, stream>>>(WK, WQKVt + 1024 * 1024, 1024, 1024);
    transpose_kernel<<<dim3(32, 32), tb, 0, stream>>>(WV, WQKVt + 2 * 1024 * 1024, 1024, 1024);
    transpose_kernel<<<dim3(32, 32), tb, 0, stream>>>(WO, WOt, 1024, 1024);
    transpose_kernel<<<dim3(128, 32), tb, 0, stream>>>(W1, W1t, 1024, 4096);
    transpose_kernel<<<dim3(32, 128), tb, 0, stream>>>(W2, W2t, 4096, 1024);
    concat3_kernel<<<dim3(12), tb, 0, stream>>>(bQ, bK, bV, bQKV);

    ln_kernel<<<8192, tb, 0, stream>>>(X, g1, be1, Xn);

    // fused QKV GEMM: N=3072, split outputs to Qb/Kb/Vb
    gemm_kernel<3><<<dim3(12, 64), dim3(512), 0, stream>>>(
        Xn, WQKVt, bQKV, nullptr, Qb, 8192, 3072, 1024);

    vtrans_kernel<<<dim3(L_ / 64, B_ * H_), tb, 0, stream>>>(Vb, Vtb);

    attn_kernel<<<dim3(L_ / 128, H_, B_), dim3(512), 0, stream>>>(
        Qb, Qb + 8192ull * 1024, Vtb, AV);

    gemm_kernel<2><<<dim3(4, 64), dim3(512), 0, stream>>>(
        AV, WOt, bO, X, out, 8192, 1024, 1024);

    ln_kernel<<<8192, tb, 0, stream>>>(out, g2, be2, Xn);

    gemm_kernel<1><<<dim3(16, 64), dim3(512), 0, stream>>>(
        Xn, W1t, b1, nullptr, H1, 8192, 4096, 1024);
    gemm_kernel<2><<<dim3(4, 64), dim3(512), 0, stream>>>(
        H1, W2t, b2, out, out, 8192, 1024, 4096);
}